// Round 4
// baseline (595.588 us; speedup 1.0000x reference)
//
#include <hip/hip_runtime.h>
#include <math.h>

// Problem constants (mirroring the reference)
#define IMG_H 480
#define IMG_W 640
#define DU    4
#define SUB_H 120          // IMG_H / DU
#define SUB_W 160          // IMG_W / DU
#define NPIX  (SUB_H * SUB_W)   // 19200
#define NSEM  16
#define NCH_IN 20          // 4 + NSEM input channels
#define VR    100
#define ZBINS 80           // MAX_VOX - MIN_VOX = 72 - (-8)
#define MIN_MAPPED 13      // 25/5 - (-8)
#define MAX_MAPPED 25      // int(89/5) - (-8)
#define NOUT  18           // 2 + NSEM
#define NCELL (VR * VR)    // 10000
#define NJOBS 16           // 16 jobs/frame -> grid = 256 blocks = 1/CU, no tail
#define BLOCK 1024

// One block per (frame, job); exactly 256 blocks so every CU runs ONE block
// (the previous 272-block grid serialized a 16-block second wave, ~2x the
// kernel time for 6% of the work).
//   job 0     : agent grid (-> dilated obstacle ch0) + explored (ch1)
//               + sem channel 15 (ch17)  -- 3 LDS grids, 120 KB
//   job 1..15 : sem channel j-1 (-> output ch 1+j) -- uses acc_s only
// All accumulation is LDS atomics; zero global atomics; each output cell is
// written exactly once with clip applied inline.
__global__ __launch_bounds__(BLOCK, 1)
void ego_map_kernel(const float* __restrict__ obs,
                    float* __restrict__ out,
                    float f_pix) {
    __shared__ float acc_s[NCELL];      // sem grid (all jobs)
    __shared__ float acc_a[NCELL];      // agent grid (job 0)
    __shared__ float acc_e[NCELL];      // explored grid (job 0)

    const int f = blockIdx.x / NJOBS;
    const int j = blockIdx.x - f * NJOBS;
    const int tid = threadIdx.x;

    for (int c = tid; c < NCELL; c += BLOCK) acc_s[c] = 0.0f;
    if (j == 0) {
        for (int c = tid; c < NCELL; c += BLOCK) acc_a[c] = 0.0f;
        for (int c = tid; c < NCELL; c += BLOCK) acc_e[c] = 0.0f;
    }
    __syncthreads();

    const float* frame = obs + (size_t)f * NCH_IN * IMG_H * IMG_W;
    const float* depth_ch = frame + (size_t)3 * IMG_H * IMG_W;
    // job0 handles sem ch 15 (input ch 19); job j>=1 handles sem ch j-1 (input ch 3+j)
    const int sem_in = (j == 0) ? (NCH_IN - 1) : (3 + j);
    const float* sem_ch = frame + (size_t)sem_in * IMG_H * IMG_W;

    for (int p = tid; p < NPIX; p += BLOCK) {
        int v = p / SUB_W;
        int u = p - v * SUB_W;
        size_t pix_off = (size_t)(v * DU) * IMG_W + (size_t)(u * DU);

        // Hoist both loads above the validity branch for ILP.
        float depth = depth_ch[pix_off];
        float s = sem_ch[pix_off];
        if (!(depth > 20.0f && depth < 500.0f)) continue;

        // Match the np reference's fp32 op order exactly (true divisions --
        // binning must be bit-exact).
        float uu = (float)(u * DU);
        float vv = (float)(v * DU);
        float X  = (uu - 320.0f) * depth / f_pix;
        float Zh = 88.0f + (240.0f - vv) * depth / f_pix;

        // np.round is half-to-even; rintf honors round-nearest-even.
        int xb = (int)rintf(X / 5.0f + 50.0f);
        int yb = (int)rintf(depth / 5.0f);
        int zb = (int)rintf(Zh / 5.0f) + 8;   // - MIN_VOX (= -8)

        if (xb < 0 || xb >= VR || yb < 0 || yb >= VR || zb < 0 || zb >= ZBINS)
            continue;

        int cell = yb * VR + xb;
        atomicAdd(&acc_s[cell], s);                    // ds_add_f32
        if (j == 0) {
            atomicAdd(&acc_e[cell], 1.0f);
            if (zb >= MIN_MAPPED && zb < MAX_MAPPED)
                atomicAdd(&acc_a[cell], 1.0f);
        }
    }
    __syncthreads();

    float* outf = out + (size_t)f * NOUT * NCELL;

    if (j == 0) {
        for (int c = tid; c < NCELL; c += BLOCK) {
            int y = c / VR;
            int x = c - y * VR;
            // 3x3 max-dilate from LDS, then clip (max/clip commute, >= 0).
            float m = 0.0f;
            int y0 = (y > 0) ? y - 1 : 0, y1 = (y < VR - 1) ? y + 1 : VR - 1;
            int x0 = (x > 0) ? x - 1 : 0, x1 = (x < VR - 1) ? x + 1 : VR - 1;
            for (int yy = y0; yy <= y1; ++yy)
                for (int xx = x0; xx <= x1; ++xx)
                    m = fmaxf(m, acc_a[yy * VR + xx]);
            outf[c] = fminf(m, 1.0f);                                   // ch0 obstacle
            outf[NCELL + c] = fminf(fmaxf(acc_e[c], 0.0f), 1.0f);       // ch1 explored
            outf[(size_t)(NOUT - 1) * NCELL + c] =
                fminf(fmaxf(acc_s[c] / 5.0f, 0.0f), 1.0f);              // ch17 sem15
        }
    } else {
        float* oc = outf + (size_t)(1 + j) * NCELL;    // sem ch j-1 -> out ch 1+j
        for (int c = tid; c < NCELL; c += BLOCK)
            oc[c] = fminf(fmaxf(acc_s[c] / 5.0f, 0.0f), 1.0f);
    }
}

extern "C" void kernel_launch(void* const* d_in, const int* in_sizes, int n_in,
                              void* d_out, int out_size, void* d_ws, size_t ws_size,
                              hipStream_t stream) {
    const float* obs = (const float*)d_in[0];
    float* out = (float*)d_out;

    int nframes = in_sizes[0] / (NCH_IN * IMG_H * IMG_W);   // B*T = 16

    // F_PIX = W/2 / tan(deg2rad(HFOV/2)) in double like numpy, then fp32.
    float f_pix = (float)(IMG_W / 2.0 / tan((79.0 / 2.0) * M_PI / 180.0));

    ego_map_kernel<<<nframes * NJOBS, BLOCK, 0, stream>>>(obs, out, f_pix);
}